// Round 24
// baseline (293.652 us; speedup 1.0000x reference)
//
#include <hip/hip_runtime.h>
#include <hip/hip_bf16.h>

// ---------------------------------------------------------------------------
// SigmoidMultiheadAttention  B=2 T=S=2048 D=1024 H=16 Dh=64  scale=1/8
// out[B,T,D] fp32 ++ attn_weights[B,T,S] fp32 concatenated in d_out.
// Round 24: R23 + XCD-aware placement in attn_fused (T1). Work assigned so
// hwid%8 (XCD) is constant per shared-K/V-panel group: each bh's 32 O-blocks
// pin to one XCD (4 panels x 512KB = 2MB <= 4MB L2); same for W (b,s-tile)
// groups. Bodies byte-identical to R23 (292us best-known).
// ws: QH | KH | VT | OH (32 MiB) [+ bf16 input mirror (30 MiB) if ws big]
// Quarantined: __launch_bounds__, 16B fp32 global loads from d_in,
// global_load_lds, d_out scratch, global atomics for aw.
// ---------------------------------------------------------------------------

#define QH_OFF  0
#define KH_OFF  4194304
#define VT_OFF  8388608
#define OH_OFF  12582912
#define XB_OFF  16777216          // bf16 input mirror base (ushort elements)
#define XQB_OFF 0
#define XKB_OFF 4194304
#define XVB_OFF 8388608
#define WQB_OFF 12582912
#define WKB_OFF 13631488
#define WVB_OFF 14680064
#define WS_MIN_BYTES (16777216ull * 2ull)                    // 32 MiB
#define WS_BIG_BYTES ((16777216ull + 15728640ull) * 2ull)    // 62 MiB

typedef short v8s  __attribute__((ext_vector_type(8)));   // 8 x bf16 fragment
typedef unsigned short v8us __attribute__((ext_vector_type(8)));
typedef float v4f  __attribute__((ext_vector_type(4)));   // MFMA accumulator
typedef unsigned int v4u __attribute__((ext_vector_type(4)));

#define MFMA_BF16(a,b,c) __builtin_amdgcn_mfma_f32_16x16x32_bf16((a),(b),(c),0,0,0)

// sigmoid(x/8) = 1/(1+exp2(-x*log2(e)/8)) — exp2+rcp builtins (~3 VALU ops)
__device__ __forceinline__ float sigmoid8(float x) {
  float e = __builtin_amdgcn_exp2f(x * -0.18033688011112042f);
  return __builtin_amdgcn_rcpf(1.0f + e);
}

__device__ __forceinline__ unsigned short f2bf(float f) {
  unsigned int u = __builtin_bit_cast(unsigned int, f);
  u += 0x7FFFu + ((u >> 16) & 1u);            // RNE
  return (unsigned short)(u >> 16);
}

// pack two floats -> one u32 of two bf16 (lo = a, hi = b)
__device__ __forceinline__ unsigned int pack2bf(float a, float b) {
  return (unsigned int)f2bf(a) | ((unsigned int)f2bf(b) << 16);
}

// ---------------------------------------------------------------------------
// cvt_inputs: fp32 -> bf16, coalesced scalar loads + coalesced 2B stores.
// ---------------------------------------------------------------------------
__global__ void cvt_inputs(const float* xq, const float* xk, const float* xv,
                           const float* wq, const float* wk, const float* wv,
                           unsigned short* __restrict__ dst)
{
  const unsigned int id = blockIdx.x * 256u + threadIdx.x;   // < 15728640
  const float* src; unsigned int off;
  if (id < 4194304u)        { src = xq; off = id; }
  else if (id < 8388608u)   { src = xk; off = id - 4194304u; }
  else if (id < 12582912u)  { src = xv; off = id - 8388608u; }
  else if (id < 13631488u)  { src = wq; off = id - 12582912u; }
  else if (id < 14680064u)  { src = wk; off = id - 13631488u; }
  else                      { src = wv; off = id - 14680064u; }
  dst[id] = f2bf(src[off]);
}

// ---------------------------------------------------------------------------
// proj_mfma_bf16: C = A.B^T + bias from bf16 mirror; 128x128 tile, BK=64,
// 4 waves (2x2), wave tile 64x64 (acc 4x4). v8us staging, LDS stride 72.
// mode 0: Q; mode 1: K; mode 2: V transposed. grid (32, 8, 3).
// ---------------------------------------------------------------------------
__global__ void proj_mfma_bf16(const unsigned short* __restrict__ xb,
                               const float* bq, const float* bk, const float* bv,
                               unsigned short* __restrict__ ws)
{
  const int tid = threadIdx.x, lane = tid & 63, wv_ = tid >> 6;
  const int wm = wv_ >> 1, wn = wv_ & 1;
  const int mode = blockIdx.z;

  const unsigned short *A, *Bw; const float* bias;
  int mt, nt;
  if (mode == 0)      { A = xb + XQB_OFF; Bw = xb + WQB_OFF; bias = bq; mt = blockIdx.x; nt = blockIdx.y; }
  else if (mode == 1) { A = xb + XKB_OFF; Bw = xb + WKB_OFF; bias = bk; mt = blockIdx.x; nt = blockIdx.y; }
  else                { A = xb + WVB_OFF; Bw = xb + XVB_OFF; bias = bv;
                        int flat = blockIdx.y * 32 + blockIdx.x; mt = flat >> 5; nt = flat & 31; }
  const int m0 = mt * 128, n0 = nt * 128;

  __shared__ alignas(16) unsigned short sA[128 * 72];
  __shared__ alignas(16) unsigned short sB[128 * 72];

  const int srow = tid >> 3;            // 0..31
  const int scol = (tid & 7) * 8;       // 0..56

  v4f acc[4][4] = {};

  for (int k0 = 0; k0 < 1024; k0 += 64) {
#pragma unroll
    for (int i = 0; i < 4; i++) {
      v8us r = *(const v8us*)&A[(size_t)(m0 + i * 32 + srow) * 1024 + k0 + scol];
      *(v8us*)&sA[(i * 32 + srow) * 72 + scol] = r;
    }
#pragma unroll
    for (int i = 0; i < 4; i++) {
      v8us r = *(const v8us*)&Bw[(size_t)(n0 + i * 32 + srow) * 1024 + k0 + scol];
      *(v8us*)&sB[(i * 32 + srow) * 72 + scol] = r;
    }
    __syncthreads();

#pragma unroll
    for (int kk = 0; kk < 2; kk++) {
      v8s af[4], bfr[4];
#pragma unroll
      for (int m = 0; m < 4; m++)
        af[m] = *(const v8s*)&sA[(wm * 64 + m * 16 + (lane & 15)) * 72 + kk * 32 + (lane >> 4) * 8];
#pragma unroll
      for (int n = 0; n < 4; n++)
        bfr[n] = *(const v8s*)&sB[(wn * 64 + n * 16 + (lane & 15)) * 72 + kk * 32 + (lane >> 4) * 8];
#pragma unroll
      for (int m = 0; m < 4; m++)
#pragma unroll
        for (int n = 0; n < 4; n++)
          acc[m][n] = MFMA_BF16(af[m], bfr[n], acc[m][n]);
    }
    __syncthreads();
  }

#pragma unroll
  for (int m = 0; m < 4; m++) {
#pragma unroll
    for (int n = 0; n < 4; n++) {
      const int gn = n0 + wn * 64 + n * 16 + (lane & 15);
#pragma unroll
      for (int j = 0; j < 4; j++) {
        const int gm = m0 + wm * 64 + m * 16 + (lane >> 4) * 4 + j;
        float val = acc[m][n][j];
        if (mode == 2) {
          val += bias[gm];
          const int hh = gm >> 6, dh = gm & 63, bb = gn >> 11, ss = gn & 2047;
          ws[(size_t)VT_OFF + ((size_t)((bb * 16 + hh) * 64 + dh)) * 2048 + ss] = f2bf(val);
        } else {
          val += bias[gn];
          const int bb = gm >> 11, tt = gm & 2047, hh = gn >> 6, dh = gn & 63;
          const size_t base = (mode == 0) ? (size_t)QH_OFF : (size_t)KH_OFF;
          ws[base + ((size_t)((bb * 16 + hh) * 2048 + tt)) * 64 + dh] = f2bf(val);
        }
      }
    }
  }
}

// ---------------------------------------------------------------------------
// proj_mfma_f32: round-8 proven fallback (scalar fp32 staging; spills but
// correct). Used when ws_size < 62 MiB. 128x64 tile, grid (32,16,3).
// ---------------------------------------------------------------------------
__global__ void proj_mfma_f32(const float* xq, const float* xk, const float* xv,
                              const float* wq, const float* wk, const float* wv,
                              const float* bq, const float* bk, const float* bv,
                              unsigned short* __restrict__ ws)
{
  const int tid = threadIdx.x, lane = tid & 63, wv_ = tid >> 6;
  const int wm = wv_ >> 1, wn = wv_ & 1;
  const int mode = blockIdx.z;

  const float *Af, *Bf, *bias;
  int mt, nt;
  if (mode == 0)      { Af = xq; Bf = wq; bias = bq; mt = blockIdx.x; nt = blockIdx.y; }
  else if (mode == 1) { Af = xk; Bf = wk; bias = bk; mt = blockIdx.x; nt = blockIdx.y; }
  else                { Af = wv; Bf = xv; bias = bv;
                        int flat = blockIdx.y * 32 + blockIdx.x; mt = flat >> 6; nt = flat & 63; }
  const int m0 = mt * 128, n0 = nt * 64;

  __shared__ alignas(16) unsigned short sA[128 * 64];
  __shared__ alignas(16) unsigned short sB[64 * 64];

  v4f acc[4][2] = {};

  for (int k0 = 0; k0 < 1024; k0 += 64) {
#pragma unroll
    for (int e = 0; e < 32; e++) {
      const int idx = e * 256 + tid;
      const int row = idx >> 6, col = idx & 63;
      sA[idx] = f2bf(Af[(size_t)(m0 + row) * 1024 + k0 + col]);
    }
#pragma unroll
    for (int e = 0; e < 16; e++) {
      const int idx = e * 256 + tid;
      const int row = idx >> 6, col = idx & 63;
      sB[idx] = f2bf(Bf[(size_t)(n0 + row) * 1024 + k0 + col]);
    }
    __syncthreads();

#pragma unroll
    for (int kk = 0; kk < 2; kk++) {
      v8s af[4], bfr[2];
#pragma unroll
      for (int m = 0; m < 4; m++)
        af[m] = *(const v8s*)&sA[(wm * 64 + m * 16 + (lane & 15)) * 64 + kk * 32 + (lane >> 4) * 8];
#pragma unroll
      for (int n = 0; n < 2; n++)
        bfr[n] = *(const v8s*)&sB[(wn * 32 + n * 16 + (lane & 15)) * 64 + kk * 32 + (lane >> 4) * 8];
#pragma unroll
      for (int m = 0; m < 4; m++)
#pragma unroll
        for (int n = 0; n < 2; n++)
          acc[m][n] = MFMA_BF16(af[m], bfr[n], acc[m][n]);
    }
    __syncthreads();
  }

#pragma unroll
  for (int m = 0; m < 4; m++) {
#pragma unroll
    for (int n = 0; n < 2; n++) {
      const int gn = n0 + wn * 32 + n * 16 + (lane & 15);
#pragma unroll
      for (int j = 0; j < 4; j++) {
        const int gm = m0 + wm * 64 + m * 16 + (lane >> 4) * 4 + j;
        float val = acc[m][n][j];
        if (mode == 2) {
          val += bias[gm];
          const int hh = gm >> 6, dh = gm & 63, bb = gn >> 11, ss = gn & 2047;
          ws[(size_t)VT_OFF + ((size_t)((bb * 16 + hh) * 64 + dh)) * 2048 + ss] = f2bf(val);
        } else {
          val += bias[gn];
          const int bb = gm >> 11, tt = gm & 2047, hh = gn >> 6, dh = gn & 63;
          const size_t base = (mode == 0) ? (size_t)QH_OFF : (size_t)KH_OFF;
          ws[base + ((size_t)((bb * 16 + hh) * 2048 + tt)) * 64 + dh] = f2bf(val);
        }
      }
    }
  }
}

// ---------------------------------------------------------------------------
// attn_fused: role-split grid (32, 64) with XCD-AWARE work assignment.
// hwid = y*32 + x; XCD = hwid % 8 (round-robin dispatch assumption).
//  role O (hwid < 1024): g = hwid>>3, r = hwid&7; bh = ((g>>5)<<3)|r,
//    t0 = (g&31)*64 — each bh's 32 t-blocks pin to one XCD (K/V panel
//    L2-resident: 4 panels x 512KB = 2MB <= 4MB).
//  role W (hwid >= 1024): same scheme over (b, s-tile) groups.
// Bodies byte-identical to R23.
// ---------------------------------------------------------------------------
__global__ void attn_fused(unsigned short* __restrict__ ws,
                           float* __restrict__ aw)
{
  __shared__ alignas(16) unsigned short Ks[128 * 64];   // 16 KB, both roles

  const int tid = threadIdx.x, lane = tid & 63, w = tid >> 6;
  const int hi = lane >> 4;             // quad group 0..3
  const int srow = tid >> 3;            // 0..31
  const int scol = (tid & 7) * 8;       // 0..56
  const int sswz = scol ^ ((srow & 7) << 3);   // staging-write swizzle
  const int xoff = (lane & 7) << 3;            // read swizzle

  const int hwid = blockIdx.y * 32 + blockIdx.x;   // 0..2047

  if (hwid < 1024) {
    // ------------------------- role O (attn_o) ---------------------------
    const int g = hwid >> 3, r = hwid & 7;
    const int bh = ((g >> 5) << 3) | r;   // 0..31, pinned to XCD r
    const int t0 = (g & 31) * 64;
    const size_t qb = (size_t)QH_OFF + (size_t)bh * 131072;
    const size_t kb = (size_t)KH_OFF + (size_t)bh * 131072;
    const size_t vb = (size_t)VT_OFF + (size_t)bh * 131072;

    v8s qf[2];
#pragma unroll
    for (int kk = 0; kk < 2; kk++)
      qf[kk] = *(const v8s*)&ws[qb + (size_t)(t0 + w * 16 + (lane & 15)) * 64 + kk * 32 + hi * 8];

    v4f oacc[4] = {};

    for (int s0 = 0; s0 < 2048; s0 += 128) {
#pragma unroll
      for (int i = 0; i < 4; i++) {
        v8us r2 = *(const v8us*)&ws[kb + (size_t)(s0 + i * 32 + srow) * 64 + scol];
        *(v8us*)&Ks[(i * 32 + srow) * 64 + sswz] = r2;
      }
      __syncthreads();

      // swapped QK: lane holds P[s = nf*16 + hi*4 + j][t = lane&15]
      unsigned int pk[8][2];
#pragma unroll
      for (int nf = 0; nf < 8; nf++) {
        v4f sc = {};
#pragma unroll
        for (int kk = 0; kk < 2; kk++) {
          v8s kf = *(const v8s*)&Ks[(nf * 16 + (lane & 15)) * 64 + ((kk * 32 + hi * 8) ^ xoff)];
          sc = MFMA_BF16(kf, qf[kk], sc);   // SWAPPED operands
        }
        pk[nf][0] = pack2bf(sigmoid8(sc[0]), sigmoid8(sc[1]));
        pk[nf][1] = pack2bf(sigmoid8(sc[2]), sigmoid8(sc[3]));
      }

      // PV: rebuild A-fragment per 32-s chunk via cross-lane shuffles.
#pragma unroll
      for (int ks = 0; ks < 4; ks++) {
        v4u wrd;
#pragma unroll
        for (int wd = 0; wd < 4; wd++) {
          const int srcLane = (lane & 15) + (((2 * hi + (wd >> 1)) & 3) << 4);
          unsigned int a = __shfl(pk[2 * ks][wd & 1], srcLane);
          unsigned int b = __shfl(pk[2 * ks + 1][wd & 1], srcLane);
          wrd[wd] = (hi < 2) ? a : b;
        }
        v8s pa = __builtin_bit_cast(v8s, wrd);
#pragma unroll
        for (int nf2 = 0; nf2 < 4; nf2++) {
          v8s vf = *(const v8s*)&ws[vb + (size_t)(nf2 * 16 + (lane & 15)) * 2048 + s0 + ks * 32 + hi * 8];
          oacc[nf2] = MFMA_BF16(pa, vf, oacc[nf2]);
        }
      }
      __syncthreads();   // protect Ks for next stage
    }

    const int b = bh >> 4, h = bh & 15;
#pragma unroll
    for (int nf = 0; nf < 4; nf++)
#pragma unroll
      for (int j = 0; j < 4; j++) {
        int t = t0 + w * 16 + hi * 4 + j;
        int dh = nf * 16 + (lane & 15);
        ws[(size_t)OH_OFF + ((size_t)(b * 2048 + t)) * 1024 + h * 64 + dh] = f2bf(oacc[nf][j]);
      }
  } else {
    // ------------------------- role W (attn_w) ---------------------------
    const int wid = hwid - 1024;
    const int g = wid >> 3, r = wid & 7;
    const int grp = ((g >> 5) << 3) | r;   // 0..31, pinned to XCD r
    const int t0 = (g & 31) * 64;
    const int b  = grp >> 4;
    const int s0 = (grp & 15) * 128;

    v4f macc[8] = {};

    for (int h = 0; h < 16; h++) {
      const size_t bh64 = (size_t)(b * 16 + h) * 131072;
#pragma unroll
      for (int i = 0; i < 4; i++) {
        v8us r2 = *(const v8us*)&ws[(size_t)KH_OFF + bh64 + (size_t)(s0 + i * 32 + srow) * 64 + scol];
        *(v8us*)&Ks[(i * 32 + srow) * 64 + sswz] = r2;
      }
      __syncthreads();

      v8s qf[2];
#pragma unroll
      for (int kk = 0; kk < 2; kk++)
        qf[kk] = *(const v8s*)&ws[(size_t)QH_OFF + bh64 + (size_t)(t0 + w * 16 + (lane & 15)) * 64 + kk * 32 + (lane >> 4) * 8];

#pragma unroll
      for (int nf = 0; nf < 8; nf++) {
        v4f sc = {};
#pragma unroll
        for (int kk = 0; kk < 2; kk++) {
          v8s kf = *(const v8s*)&Ks[(nf * 16 + (lane & 15)) * 64 + ((kk * 32 + (lane >> 4) * 8) ^ xoff)];
          sc = MFMA_BF16(qf[kk], kf, sc);
        }
#pragma unroll
        for (int j = 0; j < 4; j++)
          macc[nf][j] += sigmoid8(sc[j]);
      }
      __syncthreads();
    }

#pragma unroll
    for (int nf = 0; nf < 8; nf++)
#pragma unroll
      for (int j = 0; j < 4; j++) {
        int t = t0 + w * 16 + (lane >> 4) * 4 + j;
        int s = s0 + nf * 16 + (lane & 15);
        aw[((size_t)(b * 2048 + t)) * 2048 + s] = macc[nf][j] * 0.0625f;
      }
  }
}

// ---------------------------------------------------------------------------
// out_proj_mfma: out[m][n] = OH[m][:] . Wo[n][:] + bo[n], fp32 out.
// ---------------------------------------------------------------------------
__global__ void out_proj_mfma(const unsigned short* __restrict__ ws,
                              const float* wo, const float* bo,
                              float* __restrict__ out)
{
  const int tid = threadIdx.x, lane = tid & 63, wv_ = tid >> 6;
  const int wm = wv_ >> 1, wn = wv_ & 1;
  const int m0 = blockIdx.x * 128, n0 = blockIdx.y * 64;

  __shared__ alignas(16) unsigned short sA[128 * 72];
  __shared__ alignas(16) unsigned short sB[64 * 72];

  const int srow = tid >> 3;            // 0..31
  const int scol = (tid & 7) * 8;       // 0..56

  v4f acc[4][2] = {};

  for (int k0 = 0; k0 < 1024; k0 += 64) {
#pragma unroll
    for (int i = 0; i < 4; i++) {
      v8us r = *(const v8us*)&ws[(size_t)OH_OFF + (size_t)(m0 + i * 32 + srow) * 1024 + k0 + scol];
      *(v8us*)&sA[(i * 32 + srow) * 72 + scol] = r;
    }
#pragma unroll
    for (int e = 0; e < 16; e++) {
      const int idx = e * 256 + tid;          // 0..4095
      const int row = idx >> 6, col = idx & 63;
      sB[row * 72 + col] = f2bf(wo[(size_t)(n0 + row) * 1024 + k0 + col]);
    }
    __syncthreads();

#pragma unroll
    for (int kk = 0; kk < 2; kk++) {
      v8s af[4], bfr[2];
#pragma unroll
      for (int m = 0; m < 4; m++)
        af[m] = *(const v8s*)&sA[(wm * 64 + m * 16 + (lane & 15)) * 72 + kk * 32 + (lane >> 4) * 8];
#pragma unroll
      for (int n = 0; n < 2; n++)
        bfr[n] = *(const v8s*)&sB[(wn * 32 + n * 16 + (lane & 15)) * 72 + kk * 32 + (lane >> 4) * 8];
#pragma unroll
      for (int m = 0; m < 4; m++)
#pragma unroll
        for (int n = 0; n < 2; n++)
          acc[m][n] = MFMA_BF16(af[m], bfr[n], acc[m][n]);
    }
    __syncthreads();
  }

#pragma unroll
  for (int m = 0; m < 4; m++) {
#pragma unroll
    for (int n = 0; n < 2; n++) {
      const int gn = n0 + wn * 32 + n * 16 + (lane & 15);
#pragma unroll
      for (int j = 0; j < 4; j++) {
        const int gm = m0 + wm * 64 + m * 16 + (lane >> 4) * 4 + j;
        out[(size_t)gm * 1024 + gn] = acc[m][n][j] + bo[gn];
      }
    }
  }
}

// ---------------------------------------------------------------------------
extern "C" void kernel_launch(void* const* d_in, const int* in_sizes, int n_in,
                              void* d_out, int out_size, void* d_ws, size_t ws_size,
                              hipStream_t stream)
{
  const float* q  = (const float*)d_in[0];
  const float* k  = (const float*)d_in[1];
  const float* v  = (const float*)d_in[2];
  const float* Wq = (const float*)d_in[3];
  const float* bq = (const float*)d_in[4];
  const float* Wk = (const float*)d_in[5];
  const float* bk = (const float*)d_in[6];
  const float* Wv = (const float*)d_in[7];
  const float* bv = (const float*)d_in[8];
  const float* Wo = (const float*)d_in[9];
  const float* bo = (const float*)d_in[10];
  float* out = (float*)d_out;
  unsigned short* ws = (unsigned short*)d_ws;

  if (ws_size < WS_MIN_BYTES) return;   // insufficient scratch: fail cleanly

  if (ws_size >= WS_BIG_BYTES) {
    unsigned short* xb = ws + XB_OFF;
    cvt_inputs<<<61440, 256, 0, stream>>>(q, k, v, Wq, Wk, Wv, xb);
    proj_mfma_bf16<<<dim3(32, 8, 3), 256, 0, stream>>>(xb, bq, bk, bv, ws);
  } else {
    proj_mfma_f32<<<dim3(32, 16, 3), 256, 0, stream>>>(q, k, v, Wq, Wk, Wv,
                                                       bq, bk, bv, ws);
  }
  attn_fused<<<dim3(32, 64), 256, 0, stream>>>(ws, out + 4194304);
  out_proj_mfma<<<dim3(32, 16), 256, 0, stream>>>(ws, Wo, bo, out);
}

// Round 25
// 242.821 us; speedup vs baseline: 1.2093x; 1.2093x over previous
//
#include <hip/hip_runtime.h>
#include <hip/hip_bf16.h>

// ---------------------------------------------------------------------------
// SigmoidMultiheadAttention  B=2 T=S=2048 D=1024 H=16 Dh=64  scale=1/8
// out[B,T,D] fp32 ++ attn_weights[B,T,S] fp32 concatenated in d_out.
// Round 25: R24 + role-O t-tile 128 (two Q-row sets per wave): each staged
// K fragment feeds 2 QK MFMAs, each V fragment feeds 2 PV MFMAs — doubles
// compute per stage+barrier pair. O-grid halves to 512 (XCD pinning kept).
// Role W / proj / out_proj / cvt byte-identical to R24 (293us, passed).
// ws: QH | KH | VT | OH (32 MiB) [+ bf16 input mirror (30 MiB) if ws big]
// Quarantined: __launch_bounds__, 16B fp32 global loads from d_in,
// global_load_lds, d_out scratch, global atomics for aw.
// ---------------------------------------------------------------------------

#define QH_OFF  0
#define KH_OFF  4194304
#define VT_OFF  8388608
#define OH_OFF  12582912
#define XB_OFF  16777216          // bf16 input mirror base (ushort elements)
#define XQB_OFF 0
#define XKB_OFF 4194304
#define XVB_OFF 8388608
#define WQB_OFF 12582912
#define WKB_OFF 13631488
#define WVB_OFF 14680064
#define WS_MIN_BYTES (16777216ull * 2ull)                    // 32 MiB
#define WS_BIG_BYTES ((16777216ull + 15728640ull) * 2ull)    // 62 MiB

typedef short v8s  __attribute__((ext_vector_type(8)));   // 8 x bf16 fragment
typedef unsigned short v8us __attribute__((ext_vector_type(8)));
typedef float v4f  __attribute__((ext_vector_type(4)));   // MFMA accumulator
typedef unsigned int v4u __attribute__((ext_vector_type(4)));

#define MFMA_BF16(a,b,c) __builtin_amdgcn_mfma_f32_16x16x32_bf16((a),(b),(c),0,0,0)

// sigmoid(x/8) = 1/(1+exp2(-x*log2(e)/8)) — exp2+rcp builtins (~3 VALU ops)
__device__ __forceinline__ float sigmoid8(float x) {
  float e = __builtin_amdgcn_exp2f(x * -0.18033688011112042f);
  return __builtin_amdgcn_rcpf(1.0f + e);
}

__device__ __forceinline__ unsigned short f2bf(float f) {
  unsigned int u = __builtin_bit_cast(unsigned int, f);
  u += 0x7FFFu + ((u >> 16) & 1u);            // RNE
  return (unsigned short)(u >> 16);
}

// pack two floats -> one u32 of two bf16 (lo = a, hi = b)
__device__ __forceinline__ unsigned int pack2bf(float a, float b) {
  return (unsigned int)f2bf(a) | ((unsigned int)f2bf(b) << 16);
}

// ---------------------------------------------------------------------------
// cvt_inputs: fp32 -> bf16, coalesced scalar loads + coalesced 2B stores.
// ---------------------------------------------------------------------------
__global__ void cvt_inputs(const float* xq, const float* xk, const float* xv,
                           const float* wq, const float* wk, const float* wv,
                           unsigned short* __restrict__ dst)
{
  const unsigned int id = blockIdx.x * 256u + threadIdx.x;   // < 15728640
  const float* src; unsigned int off;
  if (id < 4194304u)        { src = xq; off = id; }
  else if (id < 8388608u)   { src = xk; off = id - 4194304u; }
  else if (id < 12582912u)  { src = xv; off = id - 8388608u; }
  else if (id < 13631488u)  { src = wq; off = id - 12582912u; }
  else if (id < 14680064u)  { src = wk; off = id - 13631488u; }
  else                      { src = wv; off = id - 14680064u; }
  dst[id] = f2bf(src[off]);
}

// ---------------------------------------------------------------------------
// proj_mfma_bf16: C = A.B^T + bias from bf16 mirror; 128x128 tile, BK=64,
// 4 waves (2x2), wave tile 64x64 (acc 4x4). v8us staging, LDS stride 72.
// mode 0: Q; mode 1: K; mode 2: V transposed. grid (32, 8, 3).
// ---------------------------------------------------------------------------
__global__ void proj_mfma_bf16(const unsigned short* __restrict__ xb,
                               const float* bq, const float* bk, const float* bv,
                               unsigned short* __restrict__ ws)
{
  const int tid = threadIdx.x, lane = tid & 63, wv_ = tid >> 6;
  const int wm = wv_ >> 1, wn = wv_ & 1;
  const int mode = blockIdx.z;

  const unsigned short *A, *Bw; const float* bias;
  int mt, nt;
  if (mode == 0)      { A = xb + XQB_OFF; Bw = xb + WQB_OFF; bias = bq; mt = blockIdx.x; nt = blockIdx.y; }
  else if (mode == 1) { A = xb + XKB_OFF; Bw = xb + WKB_OFF; bias = bk; mt = blockIdx.x; nt = blockIdx.y; }
  else                { A = xb + WVB_OFF; Bw = xb + XVB_OFF; bias = bv;
                        int flat = blockIdx.y * 32 + blockIdx.x; mt = flat >> 5; nt = flat & 31; }
  const int m0 = mt * 128, n0 = nt * 128;

  __shared__ alignas(16) unsigned short sA[128 * 72];
  __shared__ alignas(16) unsigned short sB[128 * 72];

  const int srow = tid >> 3;            // 0..31
  const int scol = (tid & 7) * 8;       // 0..56

  v4f acc[4][4] = {};

  for (int k0 = 0; k0 < 1024; k0 += 64) {
#pragma unroll
    for (int i = 0; i < 4; i++) {
      v8us r = *(const v8us*)&A[(size_t)(m0 + i * 32 + srow) * 1024 + k0 + scol];
      *(v8us*)&sA[(i * 32 + srow) * 72 + scol] = r;
    }
#pragma unroll
    for (int i = 0; i < 4; i++) {
      v8us r = *(const v8us*)&Bw[(size_t)(n0 + i * 32 + srow) * 1024 + k0 + scol];
      *(v8us*)&sB[(i * 32 + srow) * 72 + scol] = r;
    }
    __syncthreads();

#pragma unroll
    for (int kk = 0; kk < 2; kk++) {
      v8s af[4], bfr[4];
#pragma unroll
      for (int m = 0; m < 4; m++)
        af[m] = *(const v8s*)&sA[(wm * 64 + m * 16 + (lane & 15)) * 72 + kk * 32 + (lane >> 4) * 8];
#pragma unroll
      for (int n = 0; n < 4; n++)
        bfr[n] = *(const v8s*)&sB[(wn * 64 + n * 16 + (lane & 15)) * 72 + kk * 32 + (lane >> 4) * 8];
#pragma unroll
      for (int m = 0; m < 4; m++)
#pragma unroll
        for (int n = 0; n < 4; n++)
          acc[m][n] = MFMA_BF16(af[m], bfr[n], acc[m][n]);
    }
    __syncthreads();
  }

#pragma unroll
  for (int m = 0; m < 4; m++) {
#pragma unroll
    for (int n = 0; n < 4; n++) {
      const int gn = n0 + wn * 64 + n * 16 + (lane & 15);
#pragma unroll
      for (int j = 0; j < 4; j++) {
        const int gm = m0 + wm * 64 + m * 16 + (lane >> 4) * 4 + j;
        float val = acc[m][n][j];
        if (mode == 2) {
          val += bias[gm];
          const int hh = gm >> 6, dh = gm & 63, bb = gn >> 11, ss = gn & 2047;
          ws[(size_t)VT_OFF + ((size_t)((bb * 16 + hh) * 64 + dh)) * 2048 + ss] = f2bf(val);
        } else {
          val += bias[gn];
          const int bb = gm >> 11, tt = gm & 2047, hh = gn >> 6, dh = gn & 63;
          const size_t base = (mode == 0) ? (size_t)QH_OFF : (size_t)KH_OFF;
          ws[base + ((size_t)((bb * 16 + hh) * 2048 + tt)) * 64 + dh] = f2bf(val);
        }
      }
    }
  }
}

// ---------------------------------------------------------------------------
// proj_mfma_f32: round-8 proven fallback (scalar fp32 staging; spills but
// correct). Used when ws_size < 62 MiB. 128x64 tile, grid (32,16,3).
// ---------------------------------------------------------------------------
__global__ void proj_mfma_f32(const float* xq, const float* xk, const float* xv,
                              const float* wq, const float* wk, const float* wv,
                              const float* bq, const float* bk, const float* bv,
                              unsigned short* __restrict__ ws)
{
  const int tid = threadIdx.x, lane = tid & 63, wv_ = tid >> 6;
  const int wm = wv_ >> 1, wn = wv_ & 1;
  const int mode = blockIdx.z;

  const float *Af, *Bf, *bias;
  int mt, nt;
  if (mode == 0)      { Af = xq; Bf = wq; bias = bq; mt = blockIdx.x; nt = blockIdx.y; }
  else if (mode == 1) { Af = xk; Bf = wk; bias = bk; mt = blockIdx.x; nt = blockIdx.y; }
  else                { Af = wv; Bf = xv; bias = bv;
                        int flat = blockIdx.y * 32 + blockIdx.x; mt = flat >> 6; nt = flat & 63; }
  const int m0 = mt * 128, n0 = nt * 64;

  __shared__ alignas(16) unsigned short sA[128 * 64];
  __shared__ alignas(16) unsigned short sB[64 * 64];

  v4f acc[4][2] = {};

  for (int k0 = 0; k0 < 1024; k0 += 64) {
#pragma unroll
    for (int e = 0; e < 32; e++) {
      const int idx = e * 256 + tid;
      const int row = idx >> 6, col = idx & 63;
      sA[idx] = f2bf(Af[(size_t)(m0 + row) * 1024 + k0 + col]);
    }
#pragma unroll
    for (int e = 0; e < 16; e++) {
      const int idx = e * 256 + tid;
      const int row = idx >> 6, col = idx & 63;
      sB[idx] = f2bf(Bf[(size_t)(n0 + row) * 1024 + k0 + col]);
    }
    __syncthreads();

#pragma unroll
    for (int kk = 0; kk < 2; kk++) {
      v8s af[4], bfr[2];
#pragma unroll
      for (int m = 0; m < 4; m++)
        af[m] = *(const v8s*)&sA[(wm * 64 + m * 16 + (lane & 15)) * 64 + kk * 32 + (lane >> 4) * 8];
#pragma unroll
      for (int n = 0; n < 2; n++)
        bfr[n] = *(const v8s*)&sB[(wn * 32 + n * 16 + (lane & 15)) * 64 + kk * 32 + (lane >> 4) * 8];
#pragma unroll
      for (int m = 0; m < 4; m++)
#pragma unroll
        for (int n = 0; n < 2; n++)
          acc[m][n] = MFMA_BF16(af[m], bfr[n], acc[m][n]);
    }
    __syncthreads();
  }

#pragma unroll
  for (int m = 0; m < 4; m++) {
#pragma unroll
    for (int n = 0; n < 2; n++) {
      const int gn = n0 + wn * 32 + n * 16 + (lane & 15);
#pragma unroll
      for (int j = 0; j < 4; j++) {
        const int gm = m0 + wm * 64 + m * 16 + (lane >> 4) * 4 + j;
        float val = acc[m][n][j];
        if (mode == 2) {
          val += bias[gm];
          const int hh = gm >> 6, dh = gm & 63, bb = gn >> 11, ss = gn & 2047;
          ws[(size_t)VT_OFF + ((size_t)((bb * 16 + hh) * 64 + dh)) * 2048 + ss] = f2bf(val);
        } else {
          val += bias[gn];
          const int bb = gm >> 11, tt = gm & 2047, hh = gn >> 6, dh = gn & 63;
          const size_t base = (mode == 0) ? (size_t)QH_OFF : (size_t)KH_OFF;
          ws[base + ((size_t)((bb * 16 + hh) * 2048 + tt)) * 64 + dh] = f2bf(val);
        }
      }
    }
  }
}

// ---------------------------------------------------------------------------
// attn_fused: role-split grid (32, 48) with XCD-aware assignment.
//  role O (hwid < 512): t-tile 128, each wave owns 32 t-rows (2 Q sets A/B).
//    Swapped-QK; each staged K fragment feeds 2 QK MFMAs, each V fragment
//    2 PV MFMAs. bh pinned per XCD: bh = ((g>>4)<<3)|(hwid&7), t0=(g&15)*128.
//  role W (hwid >= 512): R24 attn_w, XCD-pinned (b,s-tile) groups.
// ---------------------------------------------------------------------------
__global__ void attn_fused(unsigned short* __restrict__ ws,
                           float* __restrict__ aw)
{
  __shared__ alignas(16) unsigned short Ks[128 * 64];   // 16 KB, both roles

  const int tid = threadIdx.x, lane = tid & 63, w = tid >> 6;
  const int hi = lane >> 4;             // quad group 0..3
  const int srow = tid >> 3;            // 0..31
  const int scol = (tid & 7) * 8;       // 0..56
  const int sswz = scol ^ ((srow & 7) << 3);   // staging-write swizzle
  const int xoff = (lane & 7) << 3;            // read swizzle

  const int hwid = blockIdx.y * 32 + blockIdx.x;   // 0..1535

  if (hwid < 512) {
    // --------------------- role O (attn_o, t-tile 128) -------------------
    const int g = hwid >> 3, r = hwid & 7;
    const int bh = ((g >> 4) << 3) | r;   // 0..31, pinned to XCD r
    const int t0 = (g & 15) * 128;
    const size_t qb = (size_t)QH_OFF + (size_t)bh * 131072;
    const size_t kb = (size_t)KH_OFF + (size_t)bh * 131072;
    const size_t vb = (size_t)VT_OFF + (size_t)bh * 131072;

    v8s qfA[2], qfB[2];
#pragma unroll
    for (int kk = 0; kk < 2; kk++) {
      qfA[kk] = *(const v8s*)&ws[qb + (size_t)(t0 + w * 32 + (lane & 15)) * 64 + kk * 32 + hi * 8];
      qfB[kk] = *(const v8s*)&ws[qb + (size_t)(t0 + w * 32 + 16 + (lane & 15)) * 64 + kk * 32 + hi * 8];
    }

    v4f oaccA[4] = {}, oaccB[4] = {};

    for (int s0 = 0; s0 < 2048; s0 += 128) {
#pragma unroll
      for (int i = 0; i < 4; i++) {
        v8us r2 = *(const v8us*)&ws[kb + (size_t)(s0 + i * 32 + srow) * 64 + scol];
        *(v8us*)&Ks[(i * 32 + srow) * 64 + sswz] = r2;
      }
      __syncthreads();

      // swapped QK for both t-halves; kf read once, used twice
      unsigned int pkA[8][2], pkB[8][2];
#pragma unroll
      for (int nf = 0; nf < 8; nf++) {
        v4f scA = {}, scB = {};
#pragma unroll
        for (int kk = 0; kk < 2; kk++) {
          v8s kf = *(const v8s*)&Ks[(nf * 16 + (lane & 15)) * 64 + ((kk * 32 + hi * 8) ^ xoff)];
          scA = MFMA_BF16(kf, qfA[kk], scA);
          scB = MFMA_BF16(kf, qfB[kk], scB);
        }
        pkA[nf][0] = pack2bf(sigmoid8(scA[0]), sigmoid8(scA[1]));
        pkA[nf][1] = pack2bf(sigmoid8(scA[2]), sigmoid8(scA[3]));
        pkB[nf][0] = pack2bf(sigmoid8(scB[0]), sigmoid8(scB[1]));
        pkB[nf][1] = pack2bf(sigmoid8(scB[2]), sigmoid8(scB[3]));
      }

      // PV: rebuild A-fragments via shuffles; vf read once, used twice
#pragma unroll
      for (int ks = 0; ks < 4; ks++) {
        v4u wrdA, wrdB;
#pragma unroll
        for (int wd = 0; wd < 4; wd++) {
          const int srcLane = (lane & 15) + (((2 * hi + (wd >> 1)) & 3) << 4);
          unsigned int aA = __shfl(pkA[2 * ks][wd & 1], srcLane);
          unsigned int bA = __shfl(pkA[2 * ks + 1][wd & 1], srcLane);
          wrdA[wd] = (hi < 2) ? aA : bA;
          unsigned int aB = __shfl(pkB[2 * ks][wd & 1], srcLane);
          unsigned int bB = __shfl(pkB[2 * ks + 1][wd & 1], srcLane);
          wrdB[wd] = (hi < 2) ? aB : bB;
        }
        v8s paA = __builtin_bit_cast(v8s, wrdA);
        v8s paB = __builtin_bit_cast(v8s, wrdB);
#pragma unroll
        for (int nf2 = 0; nf2 < 4; nf2++) {
          v8s vf = *(const v8s*)&ws[vb + (size_t)(nf2 * 16 + (lane & 15)) * 2048 + s0 + ks * 32 + hi * 8];
          oaccA[nf2] = MFMA_BF16(paA, vf, oaccA[nf2]);
          oaccB[nf2] = MFMA_BF16(paB, vf, oaccB[nf2]);
        }
      }
      __syncthreads();   // protect Ks for next stage
    }

    const int b = bh >> 4, h = bh & 15;
#pragma unroll
    for (int nf = 0; nf < 4; nf++)
#pragma unroll
      for (int j = 0; j < 4; j++) {
        const int dh = nf * 16 + (lane & 15);
        int tA = t0 + w * 32 + hi * 4 + j;
        ws[(size_t)OH_OFF + ((size_t)(b * 2048 + tA)) * 1024 + h * 64 + dh] = f2bf(oaccA[nf][j]);
        int tB = tA + 16;
        ws[(size_t)OH_OFF + ((size_t)(b * 2048 + tB)) * 1024 + h * 64 + dh] = f2bf(oaccB[nf][j]);
      }
  } else {
    // ------------------------- role W (attn_w) ---------------------------
    const int wid = hwid - 512;
    const int g = wid >> 3, r = wid & 7;
    const int grp = ((g >> 5) << 3) | r;   // 0..31, pinned to XCD r
    const int t0 = (g & 31) * 64;
    const int b  = grp >> 4;
    const int s0 = (grp & 15) * 128;

    v4f macc[8] = {};

    for (int h = 0; h < 16; h++) {
      const size_t bh64 = (size_t)(b * 16 + h) * 131072;
#pragma unroll
      for (int i = 0; i < 4; i++) {
        v8us r2 = *(const v8us*)&ws[(size_t)KH_OFF + bh64 + (size_t)(s0 + i * 32 + srow) * 64 + scol];
        *(v8us*)&Ks[(i * 32 + srow) * 64 + sswz] = r2;
      }
      __syncthreads();

      v8s qf[2];
#pragma unroll
      for (int kk = 0; kk < 2; kk++)
        qf[kk] = *(const v8s*)&ws[(size_t)QH_OFF + bh64 + (size_t)(t0 + w * 16 + (lane & 15)) * 64 + kk * 32 + (lane >> 4) * 8];

#pragma unroll
      for (int nf = 0; nf < 8; nf++) {
        v4f sc = {};
#pragma unroll
        for (int kk = 0; kk < 2; kk++) {
          v8s kf = *(const v8s*)&Ks[(nf * 16 + (lane & 15)) * 64 + ((kk * 32 + (lane >> 4) * 8) ^ xoff)];
          sc = MFMA_BF16(qf[kk], kf, sc);
        }
#pragma unroll
        for (int j = 0; j < 4; j++)
          macc[nf][j] += sigmoid8(sc[j]);
      }
      __syncthreads();
    }

#pragma unroll
    for (int nf = 0; nf < 8; nf++)
#pragma unroll
      for (int j = 0; j < 4; j++) {
        int t = t0 + w * 16 + (lane >> 4) * 4 + j;
        int s = s0 + nf * 16 + (lane & 15);
        aw[((size_t)(b * 2048 + t)) * 2048 + s] = macc[nf][j] * 0.0625f;
      }
  }
}

// ---------------------------------------------------------------------------
// out_proj_mfma: out[m][n] = OH[m][:] . Wo[n][:] + bo[n], fp32 out.
// ---------------------------------------------------------------------------
__global__ void out_proj_mfma(const unsigned short* __restrict__ ws,
                              const float* wo, const float* bo,
                              float* __restrict__ out)
{
  const int tid = threadIdx.x, lane = tid & 63, wv_ = tid >> 6;
  const int wm = wv_ >> 1, wn = wv_ & 1;
  const int m0 = blockIdx.x * 128, n0 = blockIdx.y * 64;

  __shared__ alignas(16) unsigned short sA[128 * 72];
  __shared__ alignas(16) unsigned short sB[64 * 72];

  const int srow = tid >> 3;            // 0..31
  const int scol = (tid & 7) * 8;       // 0..56

  v4f acc[4][2] = {};

  for (int k0 = 0; k0 < 1024; k0 += 64) {
#pragma unroll
    for (int i = 0; i < 4; i++) {
      v8us r = *(const v8us*)&ws[(size_t)OH_OFF + (size_t)(m0 + i * 32 + srow) * 1024 + k0 + scol];
      *(v8us*)&sA[(i * 32 + srow) * 72 + scol] = r;
    }
#pragma unroll
    for (int e = 0; e < 16; e++) {
      const int idx = e * 256 + tid;          // 0..4095
      const int row = idx >> 6, col = idx & 63;
      sB[row * 72 + col] = f2bf(wo[(size_t)(n0 + row) * 1024 + k0 + col]);
    }
    __syncthreads();

#pragma unroll
    for (int kk = 0; kk < 2; kk++) {
      v8s af[4], bfr[2];
#pragma unroll
      for (int m = 0; m < 4; m++)
        af[m] = *(const v8s*)&sA[(wm * 64 + m * 16 + (lane & 15)) * 72 + kk * 32 + (lane >> 4) * 8];
#pragma unroll
      for (int n = 0; n < 2; n++)
        bfr[n] = *(const v8s*)&sB[(wn * 32 + n * 16 + (lane & 15)) * 72 + kk * 32 + (lane >> 4) * 8];
#pragma unroll
      for (int m = 0; m < 4; m++)
#pragma unroll
        for (int n = 0; n < 2; n++)
          acc[m][n] = MFMA_BF16(af[m], bfr[n], acc[m][n]);
    }
    __syncthreads();
  }

#pragma unroll
  for (int m = 0; m < 4; m++) {
#pragma unroll
    for (int n = 0; n < 2; n++) {
      const int gn = n0 + wn * 32 + n * 16 + (lane & 15);
#pragma unroll
      for (int j = 0; j < 4; j++) {
        const int gm = m0 + wm * 64 + m * 16 + (lane >> 4) * 4 + j;
        out[(size_t)gm * 1024 + gn] = acc[m][n][j] + bo[gn];
      }
    }
  }
}

// ---------------------------------------------------------------------------
extern "C" void kernel_launch(void* const* d_in, const int* in_sizes, int n_in,
                              void* d_out, int out_size, void* d_ws, size_t ws_size,
                              hipStream_t stream)
{
  const float* q  = (const float*)d_in[0];
  const float* k  = (const float*)d_in[1];
  const float* v  = (const float*)d_in[2];
  const float* Wq = (const float*)d_in[3];
  const float* bq = (const float*)d_in[4];
  const float* Wk = (const float*)d_in[5];
  const float* bk = (const float*)d_in[6];
  const float* Wv = (const float*)d_in[7];
  const float* bv = (const float*)d_in[8];
  const float* Wo = (const float*)d_in[9];
  const float* bo = (const float*)d_in[10];
  float* out = (float*)d_out;
  unsigned short* ws = (unsigned short*)d_ws;

  if (ws_size < WS_MIN_BYTES) return;   // insufficient scratch: fail cleanly

  if (ws_size >= WS_BIG_BYTES) {
    unsigned short* xb = ws + XB_OFF;
    cvt_inputs<<<61440, 256, 0, stream>>>(q, k, v, Wq, Wk, Wv, xb);
    proj_mfma_bf16<<<dim3(32, 8, 3), 256, 0, stream>>>(xb, bq, bk, bv, ws);
  } else {
    proj_mfma_f32<<<dim3(32, 16, 3), 256, 0, stream>>>(q, k, v, Wq, Wk, Wv,
                                                       bq, bk, bv, ws);
  }
  attn_fused<<<dim3(32, 48), 256, 0, stream>>>(ws, out + 4194304);
  out_proj_mfma<<<dim3(32, 16), 256, 0, stream>>>(ws, Wo, bo, out);
}

// Round 26
// 240.793 us; speedup vs baseline: 1.2195x; 1.0084x over previous
//
#include <hip/hip_runtime.h>
#include <hip/hip_bf16.h>

// ---------------------------------------------------------------------------
// SigmoidMultiheadAttention  B=2 T=S=2048 D=1024 H=16 Dh=64  scale=1/8
// out[B,T,D] fp32 ++ attn_weights[B,T,S] fp32 concatenated in d_out.
// Round 26: R25 + role-W t-tile 128 (same amortization as proven O change):
// each staged K head-tile feeds 2 QK MFMA sets (A/B), W grid 1024->512.
// Grid (32,32). Role O / proj / out_proj / cvt byte-identical to R25 (243us).
// ws: QH | KH | VT | OH (32 MiB) [+ bf16 input mirror (30 MiB) if ws big]
// Quarantined: __launch_bounds__, 16B fp32 global loads from d_in,
// global_load_lds, d_out scratch, global atomics for aw.
// ---------------------------------------------------------------------------

#define QH_OFF  0
#define KH_OFF  4194304
#define VT_OFF  8388608
#define OH_OFF  12582912
#define XB_OFF  16777216          // bf16 input mirror base (ushort elements)
#define XQB_OFF 0
#define XKB_OFF 4194304
#define XVB_OFF 8388608
#define WQB_OFF 12582912
#define WKB_OFF 13631488
#define WVB_OFF 14680064
#define WS_MIN_BYTES (16777216ull * 2ull)                    // 32 MiB
#define WS_BIG_BYTES ((16777216ull + 15728640ull) * 2ull)    // 62 MiB

typedef short v8s  __attribute__((ext_vector_type(8)));   // 8 x bf16 fragment
typedef unsigned short v8us __attribute__((ext_vector_type(8)));
typedef float v4f  __attribute__((ext_vector_type(4)));   // MFMA accumulator
typedef unsigned int v4u __attribute__((ext_vector_type(4)));

#define MFMA_BF16(a,b,c) __builtin_amdgcn_mfma_f32_16x16x32_bf16((a),(b),(c),0,0,0)

// sigmoid(x/8) = 1/(1+exp2(-x*log2(e)/8)) — exp2+rcp builtins (~3 VALU ops)
__device__ __forceinline__ float sigmoid8(float x) {
  float e = __builtin_amdgcn_exp2f(x * -0.18033688011112042f);
  return __builtin_amdgcn_rcpf(1.0f + e);
}

__device__ __forceinline__ unsigned short f2bf(float f) {
  unsigned int u = __builtin_bit_cast(unsigned int, f);
  u += 0x7FFFu + ((u >> 16) & 1u);            // RNE
  return (unsigned short)(u >> 16);
}

// pack two floats -> one u32 of two bf16 (lo = a, hi = b)
__device__ __forceinline__ unsigned int pack2bf(float a, float b) {
  return (unsigned int)f2bf(a) | ((unsigned int)f2bf(b) << 16);
}

// ---------------------------------------------------------------------------
// cvt_inputs: fp32 -> bf16, coalesced scalar loads + coalesced 2B stores.
// ---------------------------------------------------------------------------
__global__ void cvt_inputs(const float* xq, const float* xk, const float* xv,
                           const float* wq, const float* wk, const float* wv,
                           unsigned short* __restrict__ dst)
{
  const unsigned int id = blockIdx.x * 256u + threadIdx.x;   // < 15728640
  const float* src; unsigned int off;
  if (id < 4194304u)        { src = xq; off = id; }
  else if (id < 8388608u)   { src = xk; off = id - 4194304u; }
  else if (id < 12582912u)  { src = xv; off = id - 8388608u; }
  else if (id < 13631488u)  { src = wq; off = id - 12582912u; }
  else if (id < 14680064u)  { src = wk; off = id - 13631488u; }
  else                      { src = wv; off = id - 14680064u; }
  dst[id] = f2bf(src[off]);
}

// ---------------------------------------------------------------------------
// proj_mfma_bf16: C = A.B^T + bias from bf16 mirror; 128x128 tile, BK=64,
// 4 waves (2x2), wave tile 64x64 (acc 4x4). v8us staging, LDS stride 72.
// mode 0: Q; mode 1: K; mode 2: V transposed. grid (32, 8, 3).
// ---------------------------------------------------------------------------
__global__ void proj_mfma_bf16(const unsigned short* __restrict__ xb,
                               const float* bq, const float* bk, const float* bv,
                               unsigned short* __restrict__ ws)
{
  const int tid = threadIdx.x, lane = tid & 63, wv_ = tid >> 6;
  const int wm = wv_ >> 1, wn = wv_ & 1;
  const int mode = blockIdx.z;

  const unsigned short *A, *Bw; const float* bias;
  int mt, nt;
  if (mode == 0)      { A = xb + XQB_OFF; Bw = xb + WQB_OFF; bias = bq; mt = blockIdx.x; nt = blockIdx.y; }
  else if (mode == 1) { A = xb + XKB_OFF; Bw = xb + WKB_OFF; bias = bk; mt = blockIdx.x; nt = blockIdx.y; }
  else                { A = xb + WVB_OFF; Bw = xb + XVB_OFF; bias = bv;
                        int flat = blockIdx.y * 32 + blockIdx.x; mt = flat >> 5; nt = flat & 31; }
  const int m0 = mt * 128, n0 = nt * 128;

  __shared__ alignas(16) unsigned short sA[128 * 72];
  __shared__ alignas(16) unsigned short sB[128 * 72];

  const int srow = tid >> 3;            // 0..31
  const int scol = (tid & 7) * 8;       // 0..56

  v4f acc[4][4] = {};

  for (int k0 = 0; k0 < 1024; k0 += 64) {
#pragma unroll
    for (int i = 0; i < 4; i++) {
      v8us r = *(const v8us*)&A[(size_t)(m0 + i * 32 + srow) * 1024 + k0 + scol];
      *(v8us*)&sA[(i * 32 + srow) * 72 + scol] = r;
    }
#pragma unroll
    for (int i = 0; i < 4; i++) {
      v8us r = *(const v8us*)&Bw[(size_t)(n0 + i * 32 + srow) * 1024 + k0 + scol];
      *(v8us*)&sB[(i * 32 + srow) * 72 + scol] = r;
    }
    __syncthreads();

#pragma unroll
    for (int kk = 0; kk < 2; kk++) {
      v8s af[4], bfr[4];
#pragma unroll
      for (int m = 0; m < 4; m++)
        af[m] = *(const v8s*)&sA[(wm * 64 + m * 16 + (lane & 15)) * 72 + kk * 32 + (lane >> 4) * 8];
#pragma unroll
      for (int n = 0; n < 4; n++)
        bfr[n] = *(const v8s*)&sB[(wn * 64 + n * 16 + (lane & 15)) * 72 + kk * 32 + (lane >> 4) * 8];
#pragma unroll
      for (int m = 0; m < 4; m++)
#pragma unroll
        for (int n = 0; n < 4; n++)
          acc[m][n] = MFMA_BF16(af[m], bfr[n], acc[m][n]);
    }
    __syncthreads();
  }

#pragma unroll
  for (int m = 0; m < 4; m++) {
#pragma unroll
    for (int n = 0; n < 4; n++) {
      const int gn = n0 + wn * 64 + n * 16 + (lane & 15);
#pragma unroll
      for (int j = 0; j < 4; j++) {
        const int gm = m0 + wm * 64 + m * 16 + (lane >> 4) * 4 + j;
        float val = acc[m][n][j];
        if (mode == 2) {
          val += bias[gm];
          const int hh = gm >> 6, dh = gm & 63, bb = gn >> 11, ss = gn & 2047;
          ws[(size_t)VT_OFF + ((size_t)((bb * 16 + hh) * 64 + dh)) * 2048 + ss] = f2bf(val);
        } else {
          val += bias[gn];
          const int bb = gm >> 11, tt = gm & 2047, hh = gn >> 6, dh = gn & 63;
          const size_t base = (mode == 0) ? (size_t)QH_OFF : (size_t)KH_OFF;
          ws[base + ((size_t)((bb * 16 + hh) * 2048 + tt)) * 64 + dh] = f2bf(val);
        }
      }
    }
  }
}

// ---------------------------------------------------------------------------
// proj_mfma_f32: round-8 proven fallback (scalar fp32 staging; spills but
// correct). Used when ws_size < 62 MiB. 128x64 tile, grid (32,16,3).
// ---------------------------------------------------------------------------
__global__ void proj_mfma_f32(const float* xq, const float* xk, const float* xv,
                              const float* wq, const float* wk, const float* wv,
                              const float* bq, const float* bk, const float* bv,
                              unsigned short* __restrict__ ws)
{
  const int tid = threadIdx.x, lane = tid & 63, wv_ = tid >> 6;
  const int wm = wv_ >> 1, wn = wv_ & 1;
  const int mode = blockIdx.z;

  const float *Af, *Bf, *bias;
  int mt, nt;
  if (mode == 0)      { Af = xq; Bf = wq; bias = bq; mt = blockIdx.x; nt = blockIdx.y; }
  else if (mode == 1) { Af = xk; Bf = wk; bias = bk; mt = blockIdx.x; nt = blockIdx.y; }
  else                { Af = wv; Bf = xv; bias = bv;
                        int flat = blockIdx.y * 32 + blockIdx.x; mt = flat >> 6; nt = flat & 63; }
  const int m0 = mt * 128, n0 = nt * 64;

  __shared__ alignas(16) unsigned short sA[128 * 64];
  __shared__ alignas(16) unsigned short sB[64 * 64];

  v4f acc[4][2] = {};

  for (int k0 = 0; k0 < 1024; k0 += 64) {
#pragma unroll
    for (int e = 0; e < 32; e++) {
      const int idx = e * 256 + tid;
      const int row = idx >> 6, col = idx & 63;
      sA[idx] = f2bf(Af[(size_t)(m0 + row) * 1024 + k0 + col]);
    }
#pragma unroll
    for (int e = 0; e < 16; e++) {
      const int idx = e * 256 + tid;
      const int row = idx >> 6, col = idx & 63;
      sB[idx] = f2bf(Bf[(size_t)(n0 + row) * 1024 + k0 + col]);
    }
    __syncthreads();

#pragma unroll
    for (int kk = 0; kk < 2; kk++) {
      v8s af[4], bfr[2];
#pragma unroll
      for (int m = 0; m < 4; m++)
        af[m] = *(const v8s*)&sA[(wm * 64 + m * 16 + (lane & 15)) * 64 + kk * 32 + (lane >> 4) * 8];
#pragma unroll
      for (int n = 0; n < 2; n++)
        bfr[n] = *(const v8s*)&sB[(wn * 32 + n * 16 + (lane & 15)) * 64 + kk * 32 + (lane >> 4) * 8];
#pragma unroll
      for (int m = 0; m < 4; m++)
#pragma unroll
        for (int n = 0; n < 2; n++)
          acc[m][n] = MFMA_BF16(af[m], bfr[n], acc[m][n]);
    }
    __syncthreads();
  }

#pragma unroll
  for (int m = 0; m < 4; m++) {
#pragma unroll
    for (int n = 0; n < 2; n++) {
      const int gn = n0 + wn * 32 + n * 16 + (lane & 15);
#pragma unroll
      for (int j = 0; j < 4; j++) {
        const int gm = m0 + wm * 64 + m * 16 + (lane >> 4) * 4 + j;
        float val = acc[m][n][j];
        if (mode == 2) {
          val += bias[gm];
          const int hh = gm >> 6, dh = gm & 63, bb = gn >> 11, ss = gn & 2047;
          ws[(size_t)VT_OFF + ((size_t)((bb * 16 + hh) * 64 + dh)) * 2048 + ss] = f2bf(val);
        } else {
          val += bias[gn];
          const int bb = gm >> 11, tt = gm & 2047, hh = gn >> 6, dh = gn & 63;
          const size_t base = (mode == 0) ? (size_t)QH_OFF : (size_t)KH_OFF;
          ws[base + ((size_t)((bb * 16 + hh) * 2048 + tt)) * 64 + dh] = f2bf(val);
        }
      }
    }
  }
}

// ---------------------------------------------------------------------------
// attn_fused: role-split grid (32, 32) with XCD-aware assignment.
//  role O (hwid < 512): t-tile 128, 2 Q sets A/B per wave; swapped-QK;
//    each staged K fragment -> 2 QK MFMAs, each V fragment -> 2 PV MFMAs.
//    bh pinned per XCD: bh = ((g>>4)<<3)|(hwid&7), t0=(g&15)*128.
//  role W (hwid >= 512): t-tile 128, 2 Q sets A/B per wave; each staged K
//    head-tile feeds 2 QK MFMA sets. XCD-pinned (b,s-tile) groups.
// ---------------------------------------------------------------------------
__global__ void attn_fused(unsigned short* __restrict__ ws,
                           float* __restrict__ aw)
{
  __shared__ alignas(16) unsigned short Ks[128 * 64];   // 16 KB, both roles

  const int tid = threadIdx.x, lane = tid & 63, w = tid >> 6;
  const int hi = lane >> 4;             // quad group 0..3
  const int srow = tid >> 3;            // 0..31
  const int scol = (tid & 7) * 8;       // 0..56
  const int sswz = scol ^ ((srow & 7) << 3);   // staging-write swizzle
  const int xoff = (lane & 7) << 3;            // read swizzle

  const int hwid = blockIdx.y * 32 + blockIdx.x;   // 0..1023

  if (hwid < 512) {
    // --------------------- role O (attn_o, t-tile 128) -------------------
    const int g = hwid >> 3, r = hwid & 7;
    const int bh = ((g >> 4) << 3) | r;   // 0..31, pinned to XCD r
    const int t0 = (g & 15) * 128;
    const size_t qb = (size_t)QH_OFF + (size_t)bh * 131072;
    const size_t kb = (size_t)KH_OFF + (size_t)bh * 131072;
    const size_t vb = (size_t)VT_OFF + (size_t)bh * 131072;

    v8s qfA[2], qfB[2];
#pragma unroll
    for (int kk = 0; kk < 2; kk++) {
      qfA[kk] = *(const v8s*)&ws[qb + (size_t)(t0 + w * 32 + (lane & 15)) * 64 + kk * 32 + hi * 8];
      qfB[kk] = *(const v8s*)&ws[qb + (size_t)(t0 + w * 32 + 16 + (lane & 15)) * 64 + kk * 32 + hi * 8];
    }

    v4f oaccA[4] = {}, oaccB[4] = {};

    for (int s0 = 0; s0 < 2048; s0 += 128) {
#pragma unroll
      for (int i = 0; i < 4; i++) {
        v8us r2 = *(const v8us*)&ws[kb + (size_t)(s0 + i * 32 + srow) * 64 + scol];
        *(v8us*)&Ks[(i * 32 + srow) * 64 + sswz] = r2;
      }
      __syncthreads();

      // swapped QK for both t-halves; kf read once, used twice
      unsigned int pkA[8][2], pkB[8][2];
#pragma unroll
      for (int nf = 0; nf < 8; nf++) {
        v4f scA = {}, scB = {};
#pragma unroll
        for (int kk = 0; kk < 2; kk++) {
          v8s kf = *(const v8s*)&Ks[(nf * 16 + (lane & 15)) * 64 + ((kk * 32 + hi * 8) ^ xoff)];
          scA = MFMA_BF16(kf, qfA[kk], scA);
          scB = MFMA_BF16(kf, qfB[kk], scB);
        }
        pkA[nf][0] = pack2bf(sigmoid8(scA[0]), sigmoid8(scA[1]));
        pkA[nf][1] = pack2bf(sigmoid8(scA[2]), sigmoid8(scA[3]));
        pkB[nf][0] = pack2bf(sigmoid8(scB[0]), sigmoid8(scB[1]));
        pkB[nf][1] = pack2bf(sigmoid8(scB[2]), sigmoid8(scB[3]));
      }

      // PV: rebuild A-fragments via shuffles; vf read once, used twice
#pragma unroll
      for (int ks = 0; ks < 4; ks++) {
        v4u wrdA, wrdB;
#pragma unroll
        for (int wd = 0; wd < 4; wd++) {
          const int srcLane = (lane & 15) + (((2 * hi + (wd >> 1)) & 3) << 4);
          unsigned int aA = __shfl(pkA[2 * ks][wd & 1], srcLane);
          unsigned int bA = __shfl(pkA[2 * ks + 1][wd & 1], srcLane);
          wrdA[wd] = (hi < 2) ? aA : bA;
          unsigned int aB = __shfl(pkB[2 * ks][wd & 1], srcLane);
          unsigned int bB = __shfl(pkB[2 * ks + 1][wd & 1], srcLane);
          wrdB[wd] = (hi < 2) ? aB : bB;
        }
        v8s paA = __builtin_bit_cast(v8s, wrdA);
        v8s paB = __builtin_bit_cast(v8s, wrdB);
#pragma unroll
        for (int nf2 = 0; nf2 < 4; nf2++) {
          v8s vf = *(const v8s*)&ws[vb + (size_t)(nf2 * 16 + (lane & 15)) * 2048 + s0 + ks * 32 + hi * 8];
          oaccA[nf2] = MFMA_BF16(paA, vf, oaccA[nf2]);
          oaccB[nf2] = MFMA_BF16(paB, vf, oaccB[nf2]);
        }
      }
      __syncthreads();   // protect Ks for next stage
    }

    const int b = bh >> 4, h = bh & 15;
#pragma unroll
    for (int nf = 0; nf < 4; nf++)
#pragma unroll
      for (int j = 0; j < 4; j++) {
        const int dh = nf * 16 + (lane & 15);
        int tA = t0 + w * 32 + hi * 4 + j;
        ws[(size_t)OH_OFF + ((size_t)(b * 2048 + tA)) * 1024 + h * 64 + dh] = f2bf(oaccA[nf][j]);
        int tB = tA + 16;
        ws[(size_t)OH_OFF + ((size_t)(b * 2048 + tB)) * 1024 + h * 64 + dh] = f2bf(oaccB[nf][j]);
      }
  } else {
    // --------------------- role W (attn_w, t-tile 128) -------------------
    const int wid = hwid - 512;           // 0..511
    const int g = wid >> 3, r = wid & 7;
    const int grp = ((g >> 4) << 3) | r;  // 0..31, pinned to XCD r
    const int t0 = (g & 15) * 128;
    const int b  = grp >> 4;
    const int s0 = (grp & 15) * 128;

    v4f maccA[8] = {}, maccB[8] = {};

    for (int h = 0; h < 16; h++) {
      const size_t bh64 = (size_t)(b * 16 + h) * 131072;
#pragma unroll
      for (int i = 0; i < 4; i++) {
        v8us r2 = *(const v8us*)&ws[(size_t)KH_OFF + bh64 + (size_t)(s0 + i * 32 + srow) * 64 + scol];
        *(v8us*)&Ks[(i * 32 + srow) * 64 + sswz] = r2;
      }
      __syncthreads();

      v8s qfA[2], qfB[2];
#pragma unroll
      for (int kk = 0; kk < 2; kk++) {
        qfA[kk] = *(const v8s*)&ws[(size_t)QH_OFF + bh64 + (size_t)(t0 + w * 32 + (lane & 15)) * 64 + kk * 32 + (lane >> 4) * 8];
        qfB[kk] = *(const v8s*)&ws[(size_t)QH_OFF + bh64 + (size_t)(t0 + w * 32 + 16 + (lane & 15)) * 64 + kk * 32 + (lane >> 4) * 8];
      }

#pragma unroll
      for (int nf = 0; nf < 8; nf++) {
        v4f scA = {}, scB = {};
#pragma unroll
        for (int kk = 0; kk < 2; kk++) {
          v8s kf = *(const v8s*)&Ks[(nf * 16 + (lane & 15)) * 64 + ((kk * 32 + (lane >> 4) * 8) ^ xoff)];
          scA = MFMA_BF16(qfA[kk], kf, scA);
          scB = MFMA_BF16(qfB[kk], kf, scB);
        }
#pragma unroll
        for (int j = 0; j < 4; j++) {
          maccA[nf][j] += sigmoid8(scA[j]);
          maccB[nf][j] += sigmoid8(scB[j]);
        }
      }
      __syncthreads();
    }

#pragma unroll
    for (int nf = 0; nf < 8; nf++)
#pragma unroll
      for (int j = 0; j < 4; j++) {
        const int s = s0 + nf * 16 + (lane & 15);
        int tA = t0 + w * 32 + (lane >> 4) * 4 + j;
        aw[((size_t)(b * 2048 + tA)) * 2048 + s] = maccA[nf][j] * 0.0625f;
        int tB = tA + 16;
        aw[((size_t)(b * 2048 + tB)) * 2048 + s] = maccB[nf][j] * 0.0625f;
      }
  }
}

// ---------------------------------------------------------------------------
// out_proj_mfma: out[m][n] = OH[m][:] . Wo[n][:] + bo[n], fp32 out.
// ---------------------------------------------------------------------------
__global__ void out_proj_mfma(const unsigned short* __restrict__ ws,
                              const float* wo, const float* bo,
                              float* __restrict__ out)
{
  const int tid = threadIdx.x, lane = tid & 63, wv_ = tid >> 6;
  const int wm = wv_ >> 1, wn = wv_ & 1;
  const int m0 = blockIdx.x * 128, n0 = blockIdx.y * 64;

  __shared__ alignas(16) unsigned short sA[128 * 72];
  __shared__ alignas(16) unsigned short sB[64 * 72];

  const int srow = tid >> 3;            // 0..31
  const int scol = (tid & 7) * 8;       // 0..56

  v4f acc[4][2] = {};

  for (int k0 = 0; k0 < 1024; k0 += 64) {
#pragma unroll
    for (int i = 0; i < 4; i++) {
      v8us r = *(const v8us*)&ws[(size_t)OH_OFF + (size_t)(m0 + i * 32 + srow) * 1024 + k0 + scol];
      *(v8us*)&sA[(i * 32 + srow) * 72 + scol] = r;
    }
#pragma unroll
    for (int e = 0; e < 16; e++) {
      const int idx = e * 256 + tid;          // 0..4095
      const int row = idx >> 6, col = idx & 63;
      sB[row * 72 + col] = f2bf(wo[(size_t)(n0 + row) * 1024 + k0 + col]);
    }
    __syncthreads();

#pragma unroll
    for (int kk = 0; kk < 2; kk++) {
      v8s af[4], bfr[2];
#pragma unroll
      for (int m = 0; m < 4; m++)
        af[m] = *(const v8s*)&sA[(wm * 64 + m * 16 + (lane & 15)) * 72 + kk * 32 + (lane >> 4) * 8];
#pragma unroll
      for (int n = 0; n < 2; n++)
        bfr[n] = *(const v8s*)&sB[(wn * 32 + n * 16 + (lane & 15)) * 72 + kk * 32 + (lane >> 4) * 8];
#pragma unroll
      for (int m = 0; m < 4; m++)
#pragma unroll
        for (int n = 0; n < 2; n++)
          acc[m][n] = MFMA_BF16(af[m], bfr[n], acc[m][n]);
    }
    __syncthreads();
  }

#pragma unroll
  for (int m = 0; m < 4; m++) {
#pragma unroll
    for (int n = 0; n < 2; n++) {
      const int gn = n0 + wn * 32 + n * 16 + (lane & 15);
#pragma unroll
      for (int j = 0; j < 4; j++) {
        const int gm = m0 + wm * 64 + m * 16 + (lane >> 4) * 4 + j;
        out[(size_t)gm * 1024 + gn] = acc[m][n][j] + bo[gn];
      }
    }
  }
}

// ---------------------------------------------------------------------------
extern "C" void kernel_launch(void* const* d_in, const int* in_sizes, int n_in,
                              void* d_out, int out_size, void* d_ws, size_t ws_size,
                              hipStream_t stream)
{
  const float* q  = (const float*)d_in[0];
  const float* k  = (const float*)d_in[1];
  const float* v  = (const float*)d_in[2];
  const float* Wq = (const float*)d_in[3];
  const float* bq = (const float*)d_in[4];
  const float* Wk = (const float*)d_in[5];
  const float* bk = (const float*)d_in[6];
  const float* Wv = (const float*)d_in[7];
  const float* bv = (const float*)d_in[8];
  const float* Wo = (const float*)d_in[9];
  const float* bo = (const float*)d_in[10];
  float* out = (float*)d_out;
  unsigned short* ws = (unsigned short*)d_ws;

  if (ws_size < WS_MIN_BYTES) return;   // insufficient scratch: fail cleanly

  if (ws_size >= WS_BIG_BYTES) {
    unsigned short* xb = ws + XB_OFF;
    cvt_inputs<<<61440, 256, 0, stream>>>(q, k, v, Wq, Wk, Wv, xb);
    proj_mfma_bf16<<<dim3(32, 8, 3), 256, 0, stream>>>(xb, bq, bk, bv, ws);
  } else {
    proj_mfma_f32<<<dim3(32, 16, 3), 256, 0, stream>>>(q, k, v, Wq, Wk, Wv,
                                                       bq, bk, bv, ws);
  }
  attn_fused<<<dim3(32, 32), 256, 0, stream>>>(ws, out + 4194304);
  out_proj_mfma<<<dim3(32, 16), 256, 0, stream>>>(ws, Wo, bo, out);
}